// Round 7
// baseline (188.918 us; speedup 1.0000x reference)
//
#include <hip/hip_runtime.h>
#include <math.h>

// dims: B=8, L=96, D=512, R=64, NTYPES=47, NLAYERS=3
#define SCALE 0.044194173824159216f   // 1/sqrt(512)
#define INVS  0.9995003746879289f     // 1/sqrt(1.001)

// ws float offsets
#define SEQ_OFF  0          // 393216
#define AGG_OFF  393216     // 393216
#define G_OFF    786432     // 2209 (pad 2304)
#define POOL_OFF 788736     // 3*8*512
#define ENSW_OFF 801024     // 3
#define CNT_OFF  801028     // 8

#define F4FMA(acc, s, ww) { acc.x = fmaf(s, ww.x, acc.x); acc.y = fmaf(s, ww.y, acc.y); \
                            acc.z = fmaf(s, ww.z, acc.z); acc.w = fmaf(s, ww.w, acc.w); }

__device__ __forceinline__ float wave_sum(float v) {
  #pragma unroll
  for (int o = 32; o; o >>= 1) v += __shfl_xor(v, o);
  return v;
}
__device__ __forceinline__ float wave_max(float v) {
  #pragma unroll
  for (int o = 32; o; o >>= 1) v = fmaxf(v, __shfl_xor(v, o));
  return v;
}

// ---------------------------------------------------------------------------
// prep: seq-norm + G table + rcnt + ensemble softmax.  grid 512x256
// ---------------------------------------------------------------------------
__global__ __launch_bounds__(256) void k_prep(
    const float* __restrict__ text, const float* __restrict__ mask,
    const float* __restrict__ E, const float* __restrict__ gamma,
    const float* __restrict__ beta, const float* __restrict__ ensl,
    float* __restrict__ ws)
{
  const int blk = blockIdx.x, tid = threadIdx.x;
  const int gt = blk * 256 + tid;
  {
    const float4* T4 = (const float4*)text;
    float4* S4 = (float4*)(ws + SEQ_OFF);
    const float4* G4 = (const float4*)gamma;
    const float4* B4 = (const float4*)beta;
    for (int i4 = gt; i4 < 98304; i4 += 512 * 256) {
      float4 t = T4[i4];
      const int gi = i4 & 127;
      const float4 g4 = G4[gi], b4 = B4[gi];
      float4 o;
      o.x = fmaf(t.x, g4.x * INVS, b4.x);
      o.y = fmaf(t.y, g4.y * INVS, b4.y);
      o.z = fmaf(t.z, g4.z * INVS, b4.z);
      o.w = fmaf(t.w, g4.w * INVS, b4.w);
      S4[i4] = o;
    }
  }
  // G[t1,t2] = dot(E[t1],E[t2]); one wave per entry
  const int wg = gt >> 6, lane = tid & 63;
  float* G = ws + G_OFF;
  for (int g = wg; g < 2209; g += 2048) {
    const int t1 = g / 47, t2 = g - t1 * 47;
    const float4* e1 = (const float4*)E + t1 * 128;
    const float4* e2 = (const float4*)E + t2 * 128;
    const float4 a0 = e1[lane], a1 = e1[64 + lane];
    const float4 b0 = e2[lane], b1 = e2[64 + lane];
    float d = a0.x * b0.x;
    d = fmaf(a0.y, b0.y, d); d = fmaf(a0.z, b0.z, d); d = fmaf(a0.w, b0.w, d);
    d = fmaf(a1.x, b1.x, d); d = fmaf(a1.y, b1.y, d);
    d = fmaf(a1.z, b1.z, d); d = fmaf(a1.w, b1.w, d);
    d = wave_sum(d);
    if (lane == 0) G[g] = d;
  }
  if (blk == 0) {
    if (tid < 8) {
      float c = 0.f;
      for (int i = 0; i < 96; ++i) c += (mask[tid * 96 + i] != 0.f) ? 1.f : 0.f;
      (ws + CNT_OFF)[tid] = 1.f / (c + 1e-10f);
    }
    if (tid == 8) {
      const float e0 = ensl[0], e1 = ensl[1], e2 = ensl[2];
      const float m = fmaxf(e0, fmaxf(e1, e2));
      const float x0 = expf(e0 - m), x1 = expf(e1 - m), x2 = expf(e2 - m);
      const float s = x0 + x1 + x2;
      (ws + ENSW_OFF)[0] = x0 / s;
      (ws + ENSW_OFF)[1] = x1 / s;
      (ws + ENSW_OFF)[2] = x2 / s;
    }
  }
}

// pools[b,d] = (sum_i mask*seq)/cnt(b); u in [0,16): b=u>>1, d-half=u&1
__device__ __forceinline__ void pool_unit(int u, int tid,
    const float* __restrict__ seq, const float* __restrict__ mask,
    const float* __restrict__ rcnt, float* __restrict__ dst)
{
  const int b = u >> 1;
  const int d = (u & 1) * 256 + tid;
  float acc = 0.f;
  #pragma unroll 4
  for (int i = 0; i < 96; ++i)
    acc = fmaf(mask[b * 96 + i], seq[(b * 96 + i) * 512 + d], acc);
  dst[b * 512 + d] = acc * rcnt[b];
}

// ---------------------------------------------------------------------------
// attn: 2 query rows per block (blk = ip*8 + b -> XCD b holds batch b).
// 4 waves j-split scores (both rows) -> bias -> softmax (waves 0/1)
// -> agg: wave (row = w&1, d-half = w>>1), full float4.
// blocks 384..399: pool of previous layer's seq (when do_pool). grid 400x256
// ---------------------------------------------------------------------------
__global__ __launch_bounds__(256) void k_attn(
    const float* __restrict__ seq, float* __restrict__ agg,
    const float* __restrict__ adj, const float* __restrict__ E,
    const int* __restrict__ dv, const float* __restrict__ ws,
    const float* __restrict__ mask, float* __restrict__ pool_dst, int do_pool)
{
  const int blk = blockIdx.x, tid = threadIdx.x;
  if (blk >= 384) {
    if (do_pool) pool_unit(blk - 384, tid, seq, mask, ws + CNT_OFF, pool_dst);
    return;
  }
  __shared__ float s_sc[2][96];
  __shared__ float s_at[2][96];
  __shared__ int   s_vt[2][96];
  const int b = blk & 7, ip = blk >> 3;
  const int iA = ip * 2, iB = iA + 1;
  const int w = tid >> 6, lane = tid & 63;
  const float* G = ws + G_OFF;
  const float4* seq4 = (const float4*)seq + (size_t)b * 96 * 128;

  const float4 qA0 = seq4[iA * 128 + lane];
  const float4 qA1 = seq4[iA * 128 + 64 + lane];
  const float4 qB0 = seq4[iB * 128 + lane];
  const float4 qB1 = seq4[iB * 128 + 64 + lane];
  // scores for both rows: wave w handles j = w, w+4, ...
  #pragma unroll 2
  for (int j = w; j < 96; j += 4) {
    const float4 x0 = seq4[j * 128 + lane];
    const float4 x1 = seq4[j * 128 + 64 + lane];
    float dA = qA0.x * x0.x;
    dA = fmaf(qA0.y, x0.y, dA); dA = fmaf(qA0.z, x0.z, dA); dA = fmaf(qA0.w, x0.w, dA);
    dA = fmaf(qA1.x, x1.x, dA); dA = fmaf(qA1.y, x1.y, dA);
    dA = fmaf(qA1.z, x1.z, dA); dA = fmaf(qA1.w, x1.w, dA);
    float dB = qB0.x * x0.x;
    dB = fmaf(qB0.y, x0.y, dB); dB = fmaf(qB0.z, x0.z, dB); dB = fmaf(qB0.w, x0.w, dB);
    dB = fmaf(qB1.x, x1.x, dB); dB = fmaf(qB1.y, x1.y, dB);
    dB = fmaf(qB1.z, x1.z, dB); dB = fmaf(qB1.w, x1.w, dB);
    dA = wave_sum(dA);
    dB = wave_sum(dB);
    if (lane == 0) { s_sc[0][j] = dA; s_sc[1][j] = dB; }
  }
  __syncthreads();
  // dep bias + scale; stash transposed dv
  const int* dvb = dv + b * 9216;
  if (tid < 192) {
    const int row = (tid >= 96) ? 1 : 0, jj = tid - row * 96;
    const int i = iA + row;
    const int v1 = dvb[i * 96 + jj];
    const int v2 = dvb[jj * 96 + i];
    s_vt[row][jj] = v2;
    const float bs = (v1 > 0 && v2 > 0) ? G[v1 * 47 + v2] : 0.f;
    s_sc[row][jj] = (s_sc[row][jj] + bs) * SCALE;
  }
  __syncthreads();
  if (w < 2) {
    const int i = iA + w;
    const float v0 = s_sc[w][lane];
    const float v1 = (lane < 32) ? s_sc[w][64 + lane] : -3.0e38f;
    const float mx = wave_max(fmaxf(v0, v1));
    const float e0 = expf(v0 - mx);
    const float e1 = (lane < 32) ? expf(v1 - mx) : 0.f;
    const float s = wave_sum(e0 + e1);
    const float inv = 1.f / s;
    const float* ad = adj + (b * 96 + i) * 96;
    s_at[w][lane] = e0 * inv * ad[lane];
    if (lane < 32) s_at[w][64 + lane] = e1 * inv * ad[64 + lane];
  }
  __syncthreads();
  // agg: wave -> (row = w&1, d-half = w>>1); lane covers one float4
  const int row = w & 1, i = iA + row;
  const int d4 = (w >> 1) * 64 + lane;
  const float4* E4 = (const float4*)E;
  float4 ac = {0.f, 0.f, 0.f, 0.f};
  for (int j = 0; j < 96; ++j) {
    const float a = s_at[row][j];
    if (a != 0.f) {                                   // wave-uniform, ~10% taken
      float4 x = seq4[j * 128 + d4];
      const int vt = s_vt[row][j];
      if (vt > 0) {
        const float4 e4 = E4[vt * 128 + d4];
        x.x += e4.x; x.y += e4.y; x.z += e4.z; x.w += e4.w;
      }
      F4FMA(ac, a, x);
    }
  }
  ((float4*)agg)[(size_t)(b * 96 + i) * 128 + d4] = ac;
}

// ---------------------------------------------------------------------------
// gemm: Out = relu(A @ W + bias). Tiles 6x64, 1024 blocks (4/CU, 16 waves/CU).
// blk = b + 8*rr + 128*ct (batch-XCD pinned). threads = 16 colf4 x 16 kq.
// ---------------------------------------------------------------------------
__global__ __launch_bounds__(256) void k_gemm(
    const float* __restrict__ A, const float* __restrict__ W,
    const float* __restrict__ bias, float* __restrict__ Out)
{
  __shared__ __align__(16) float s_a[6 * 512];        // 12 KB
  __shared__ __align__(16) float4 s_p[16 * 6 * 16];   // 24 KB
  const int blk = blockIdx.x, tid = threadIdx.x;
  const int b = blk & 7, rr = (blk >> 3) & 15, ct = blk >> 7;   // ct 0..7
  const int r0 = (b * 16 + rr) * 6, c0 = ct * 64;
  {
    const float4* A4 = (const float4*)(A + r0 * 512);
    float4* sa4 = (float4*)s_a;
    sa4[tid] = A4[tid];
    sa4[tid + 256] = A4[tid + 256];
    sa4[tid + 512] = A4[tid + 512];
  }
  __syncthreads();
  const int cq = tid & 15, kq = tid >> 4;
  const float4* W4 = (const float4*)W + ct * 16 + cq;   // + k*128
  float4 acc[6];
  #pragma unroll
  for (int r = 0; r < 6; ++r) { acc[r].x = 0.f; acc[r].y = 0.f; acc[r].z = 0.f; acc[r].w = 0.f; }
  const float4* sa4 = (const float4*)s_a;
  #pragma unroll 2
  for (int k4 = kq * 8; k4 < kq * 8 + 8; ++k4) {
    const float4 w0 = W4[(k4 * 4 + 0) * 128];
    const float4 w1 = W4[(k4 * 4 + 1) * 128];
    const float4 w2 = W4[(k4 * 4 + 2) * 128];
    const float4 w3 = W4[(k4 * 4 + 3) * 128];
    #pragma unroll
    for (int r = 0; r < 6; ++r) {
      const float4 a4 = sa4[r * 128 + k4];
      F4FMA(acc[r], a4.x, w0); F4FMA(acc[r], a4.y, w1);
      F4FMA(acc[r], a4.z, w2); F4FMA(acc[r], a4.w, w3);
    }
  }
  #pragma unroll
  for (int r = 0; r < 6; ++r) s_p[(kq * 6 + r) * 16 + cq] = acc[r];
  __syncthreads();
  if (tid < 96) {
    const int r = tid >> 4, c = tid & 15;
    float4 s = s_p[r * 16 + c];
    #pragma unroll
    for (int q = 1; q < 16; ++q) {
      const float4 p = s_p[(q * 6 + r) * 16 + c];
      s.x += p.x; s.y += p.y; s.z += p.z; s.w += p.w;
    }
    const float4 bv = ((const float4*)(bias + c0))[c];
    float4 o;
    o.x = fmaxf(s.x + bv.x, 0.f);
    o.y = fmaxf(s.y + bv.y, 0.f);
    o.z = fmaxf(s.z + bv.z, 0.f);
    o.w = fmaxf(s.w + bv.w, 0.f);
    ((float4*)(Out + (size_t)(r0 + r) * 512 + c0))[c] = o;
  }
}

// ---------------------------------------------------------------------------
// final: pool2 (per block) + ensemble + fc.  grid 8x256
// ---------------------------------------------------------------------------
__global__ __launch_bounds__(256) void k_final(
    const float* __restrict__ seq, const float* __restrict__ mask,
    const float* __restrict__ ws, const float* __restrict__ fcW,
    const float* __restrict__ fcb, float* __restrict__ out)
{
  __shared__ float s_ens[512];
  __shared__ float s_red[256];
  const int b = blockIdx.x, tid = threadIdx.x;
  const float* ensw = ws + ENSW_OFF;
  const float* rcnt = ws + CNT_OFF;
  const float* p0 = ws + POOL_OFF + b * 512;
  const float* p1 = ws + POOL_OFF + 4096 + b * 512;
  float2 acc; acc.x = 0.f; acc.y = 0.f;
  const float2* seqb2 = (const float2*)(seq + (size_t)b * 96 * 512);
  #pragma unroll 4
  for (int i = 0; i < 96; ++i) {
    const float m = mask[b * 96 + i];
    const float2 x = seqb2[i * 256 + tid];
    acc.x = fmaf(m, x.x, acc.x);
    acc.y = fmaf(m, x.y, acc.y);
  }
  const float rc = rcnt[b];
  const float w0 = ensw[0], w1 = ensw[1], w2 = ensw[2];
  s_ens[tid * 2]     = w0 * p0[tid * 2]     + w1 * p1[tid * 2]     + w2 * acc.x * rc;
  s_ens[tid * 2 + 1] = w0 * p0[tid * 2 + 1] + w1 * p1[tid * 2 + 1] + w2 * acc.y * rc;
  __syncthreads();
  const int r = tid & 63, dq = tid >> 6;
  float a = 0.f;
  #pragma unroll 4
  for (int d = dq * 128; d < dq * 128 + 128; ++d)
    a = fmaf(s_ens[d], fcW[d * 64 + r], a);
  s_red[tid] = a;
  __syncthreads();
  if (tid < 64)
    out[b * 64 + tid] = fcb[tid] + s_red[tid] + s_red[64 + tid]
                      + s_red[128 + tid] + s_red[192 + tid];
}

extern "C" void kernel_launch(void* const* d_in, const int* in_sizes, int n_in,
                              void* d_out, int out_size, void* d_ws, size_t ws_size,
                              hipStream_t stream)
{
  const float* text  = (const float*)d_in[0];
  const float* mask  = (const float*)d_in[1];
  const float* adj   = (const float*)d_in[2];
  const float* E     = (const float*)d_in[3];
  const float* gamma = (const float*)d_in[4];
  const float* beta  = (const float*)d_in[5];
  const float* Wst   = (const float*)d_in[6];
  const float* bst   = (const float*)d_in[7];
  const float* ensl  = (const float*)d_in[8];
  const float* fcW   = (const float*)d_in[9];
  const float* fcb   = (const float*)d_in[10];
  const int*   dv    = (const int*)d_in[11];
  float* ws  = (float*)d_ws;
  float* out = (float*)d_out;

  float* seq = ws + SEQ_OFF;
  float* agg = ws + AGG_OFF;

  k_prep<<<dim3(512), dim3(256), 0, stream>>>(text, mask, E, gamma, beta, ensl, ws);
  for (int l = 0; l < 3; ++l) {
    k_attn<<<dim3(400), dim3(256), 0, stream>>>(
        seq, agg, adj, E, dv, ws, mask,
        ws + POOL_OFF + (l > 0 ? (l - 1) * 4096 : 0), l > 0 ? 1 : 0);
    k_gemm<<<dim3(1024), dim3(256), 0, stream>>>(
        agg, Wst + l * 262144, bst + l * 512, seq);
  }
  k_final<<<dim3(8), dim3(256), 0, stream>>>(seq, mask, ws, fcW, fcb, out);
}

// Round 10
// 168.795 us; speedup vs baseline: 1.1192x; 1.1192x over previous
//
#include <hip/hip_runtime.h>
#include <math.h>

// dims: B=8, L=96, D=512, R=64, NTYPES=47, NLAYERS=3
#define SCALE 0.044194173824159216f   // 1/sqrt(512)
#define INVS  0.9995003746879289f     // 1/sqrt(1.001)

// ws float offsets
#define SEQ_OFF  0          // 393216
#define AGG_OFF  393216     // 393216
#define G_OFF    786432     // 2209 (pad 2304)
#define POOL_OFF 788736     // 3*8*512
#define ENSW_OFF 801024     // 3
#define CNT_OFF  801028     // 8

#define F4FMA(acc, s, ww) { acc.x = fmaf(s, ww.x, acc.x); acc.y = fmaf(s, ww.y, acc.y); \
                            acc.z = fmaf(s, ww.z, acc.z); acc.w = fmaf(s, ww.w, acc.w); }

__device__ __forceinline__ float wave_sum(float v) {
  #pragma unroll
  for (int o = 32; o; o >>= 1) v += __shfl_xor(v, o);
  return v;
}
__device__ __forceinline__ float wave_max(float v) {
  #pragma unroll
  for (int o = 32; o; o >>= 1) v = fmaxf(v, __shfl_xor(v, o));
  return v;
}

// ---------------------------------------------------------------------------
// prep: seq-norm + G table + rcnt + ensemble softmax.  grid 512x256
// ---------------------------------------------------------------------------
__global__ __launch_bounds__(256) void k_prep(
    const float* __restrict__ text, const float* __restrict__ mask,
    const float* __restrict__ E, const float* __restrict__ gamma,
    const float* __restrict__ beta, const float* __restrict__ ensl,
    float* __restrict__ ws)
{
  const int blk = blockIdx.x, tid = threadIdx.x;
  const int gt = blk * 256 + tid;
  {
    const float4* T4 = (const float4*)text;
    float4* S4 = (float4*)(ws + SEQ_OFF);
    const float4* G4 = (const float4*)gamma;
    const float4* B4 = (const float4*)beta;
    for (int i4 = gt; i4 < 98304; i4 += 512 * 256) {
      float4 t = T4[i4];
      const int gi = i4 & 127;
      const float4 g4 = G4[gi], b4 = B4[gi];
      float4 o;
      o.x = fmaf(t.x, g4.x * INVS, b4.x);
      o.y = fmaf(t.y, g4.y * INVS, b4.y);
      o.z = fmaf(t.z, g4.z * INVS, b4.z);
      o.w = fmaf(t.w, g4.w * INVS, b4.w);
      S4[i4] = o;
    }
  }
  // G[t1,t2] = dot(E[t1],E[t2]); one wave per entry
  const int wg = gt >> 6, lane = tid & 63;
  float* G = ws + G_OFF;
  for (int g = wg; g < 2209; g += 2048) {
    const int t1 = g / 47, t2 = g - t1 * 47;
    const float4* e1 = (const float4*)E + t1 * 128;
    const float4* e2 = (const float4*)E + t2 * 128;
    const float4 a0 = e1[lane], a1 = e1[64 + lane];
    const float4 b0 = e2[lane], b1 = e2[64 + lane];
    float d = a0.x * b0.x;
    d = fmaf(a0.y, b0.y, d); d = fmaf(a0.z, b0.z, d); d = fmaf(a0.w, b0.w, d);
    d = fmaf(a1.x, b1.x, d); d = fmaf(a1.y, b1.y, d);
    d = fmaf(a1.z, b1.z, d); d = fmaf(a1.w, b1.w, d);
    d = wave_sum(d);
    if (lane == 0) G[g] = d;
  }
  if (blk == 0) {
    if (tid < 8) {
      float c = 0.f;
      for (int i = 0; i < 96; ++i) c += (mask[tid * 96 + i] != 0.f) ? 1.f : 0.f;
      (ws + CNT_OFF)[tid] = 1.f / (c + 1e-10f);
    }
    if (tid == 8) {
      const float e0 = ensl[0], e1 = ensl[1], e2 = ensl[2];
      const float m = fmaxf(e0, fmaxf(e1, e2));
      const float x0 = expf(e0 - m), x1 = expf(e1 - m), x2 = expf(e2 - m);
      const float s = x0 + x1 + x2;
      (ws + ENSW_OFF)[0] = x0 / s;
      (ws + ENSW_OFF)[1] = x1 / s;
      (ws + ENSW_OFF)[2] = x2 / s;
    }
  }
}

// pools[b,d] = (sum_i mask*seq)/cnt(b); u in [0,16): b=u>>1, d-half=u&1
__device__ __forceinline__ void pool_unit(int u, int tid,
    const float* __restrict__ seq, const float* __restrict__ mask,
    const float* __restrict__ rcnt, float* __restrict__ dst)
{
  const int b = u >> 1;
  const int d = (u & 1) * 256 + tid;
  float acc = 0.f;
  #pragma unroll 4
  for (int i = 0; i < 96; ++i)
    acc = fmaf(mask[b * 96 + i], seq[(b * 96 + i) * 512 + d], acc);
  dst[b * 512 + d] = acc * rcnt[b];
}

// ---------------------------------------------------------------------------
// attn: 1 query row per block (blk = i*8 + b -> XCD b holds batch b).
// 4 waves j-split scores -> bias -> softmax(wave0) -> COMPRESS nz attn
// entries to LDS -> branch-free agg over nnz (~10) entries, float2/thread.
// blocks 768..783: pool of previous layer's seq (when do_pool). grid 784x256
// ---------------------------------------------------------------------------
__global__ __launch_bounds__(256) void k_attn(
    const float* __restrict__ seq, float* __restrict__ agg,
    const float* __restrict__ adj, const float* __restrict__ E,
    const int* __restrict__ dv, const float* __restrict__ ws,
    const float* __restrict__ mask, float* __restrict__ pool_dst, int do_pool)
{
  const int blk = blockIdx.x, tid = threadIdx.x;
  if (blk >= 768) {
    if (do_pool) pool_unit(blk - 768, tid, seq, mask, ws + CNT_OFF, pool_dst);
    return;
  }
  __shared__ float s_sc[96];
  __shared__ int   s_vt[96];
  __shared__ float s_ca[96];     // compressed attn value
  __shared__ int   s_cj[96];     // compressed j index
  __shared__ int   s_cv[96];     // compressed vt
  __shared__ int   s_cnt;
  const int b = blk & 7, i = blk >> 3;
  const int w = tid >> 6, lane = tid & 63;
  const float* G = ws + G_OFF;
  const float4* seq4 = (const float4*)seq + (size_t)b * 96 * 128;

  if (tid == 0) s_cnt = 0;
  const float4 q0 = seq4[i * 128 + lane];
  const float4 q1 = seq4[i * 128 + 64 + lane];
  // scores: wave w handles j = w, w+4, ...
  #pragma unroll 2
  for (int j = w; j < 96; j += 4) {
    const float4 x0 = seq4[j * 128 + lane];
    const float4 x1 = seq4[j * 128 + 64 + lane];
    float d = q0.x * x0.x;
    d = fmaf(q0.y, x0.y, d); d = fmaf(q0.z, x0.z, d); d = fmaf(q0.w, x0.w, d);
    d = fmaf(q1.x, x1.x, d); d = fmaf(q1.y, x1.y, d);
    d = fmaf(q1.z, x1.z, d); d = fmaf(q1.w, x1.w, d);
    d = wave_sum(d);
    if (lane == 0) s_sc[j] = d;
  }
  __syncthreads();
  // dep bias + scale; stash transposed dv
  const int* dvb = dv + b * 9216;
  if (tid < 96) {
    const int v1 = dvb[i * 96 + tid];
    const int v2 = dvb[tid * 96 + i];
    s_vt[tid] = v2;
    const float bs = (v1 > 0 && v2 > 0) ? G[v1 * 47 + v2] : 0.f;
    s_sc[tid] = (s_sc[tid] + bs) * SCALE;
  }
  __syncthreads();
  // softmax + *adj + compaction (wave 0)
  if (w == 0) {
    const float v0 = s_sc[lane];
    const float v1 = (lane < 32) ? s_sc[64 + lane] : -3.0e38f;
    const float mx = wave_max(fmaxf(v0, v1));
    const float e0 = expf(v0 - mx);
    const float e1 = (lane < 32) ? expf(v1 - mx) : 0.f;
    const float s = wave_sum(e0 + e1);
    const float inv = 1.f / s;
    const float* ad = adj + (b * 96 + i) * 96;
    const float a0 = e0 * inv * ad[lane];
    if (a0 != 0.f) {
      const int p = atomicAdd(&s_cnt, 1);
      s_cj[p] = lane; s_ca[p] = a0; s_cv[p] = s_vt[lane];
    }
    if (lane < 32) {
      const float a1 = e1 * inv * ad[64 + lane];
      if (a1 != 0.f) {
        const int p = atomicAdd(&s_cnt, 1);
        s_cj[p] = 64 + lane; s_ca[p] = a1; s_cv[p] = s_vt[64 + lane];
      }
    }
  }
  __syncthreads();
  // branch-free agg over compressed list; thread owns float2 (512 cols)
  const int nnz = s_cnt;
  const float2* seq2 = (const float2*)seq + (size_t)b * 96 * 256;
  const float2* E2v = (const float2*)E;
  float ax = 0.f, ay = 0.f;
  for (int t = 0; t < nnz; ++t) {
    const float a = s_ca[t];
    const int j = s_cj[t];
    const int vt = s_cv[t];
    const float2 x = seq2[j * 256 + tid];
    const float2 ev = E2v[vt * 256 + tid];
    const float sel = (vt > 0) ? 1.f : 0.f;
    ax = fmaf(a, fmaf(sel, ev.x, x.x), ax);
    ay = fmaf(a, fmaf(sel, ev.y, x.y), ay);
  }
  float2 o; o.x = ax; o.y = ay;
  ((float2*)agg)[(size_t)(b * 96 + i) * 256 + tid] = o;
}

// ---------------------------------------------------------------------------
// gemm: Out = relu(A @ W + bias). Tiles 6x64, 1024 blocks (4/CU, 16 waves/CU).
// blk = b + 8*rr + 128*ct (batch-XCD pinned). threads = 16 colf4 x 16 kq.
// ---------------------------------------------------------------------------
__global__ __launch_bounds__(256) void k_gemm(
    const float* __restrict__ A, const float* __restrict__ W,
    const float* __restrict__ bias, float* __restrict__ Out)
{
  __shared__ __align__(16) float s_a[6 * 512];        // 12 KB
  __shared__ __align__(16) float4 s_p[16 * 6 * 16];   // 24 KB
  const int blk = blockIdx.x, tid = threadIdx.x;
  const int b = blk & 7, rr = (blk >> 3) & 15, ct = blk >> 7;   // ct 0..7
  const int r0 = (b * 16 + rr) * 6, c0 = ct * 64;
  {
    const float4* A4 = (const float4*)(A + r0 * 512);
    float4* sa4 = (float4*)s_a;
    sa4[tid] = A4[tid];
    sa4[tid + 256] = A4[tid + 256];
    sa4[tid + 512] = A4[tid + 512];
  }
  __syncthreads();
  const int cq = tid & 15, kq = tid >> 4;
  const float4* W4 = (const float4*)W + ct * 16 + cq;   // + k*128
  float4 acc[6];
  #pragma unroll
  for (int r = 0; r < 6; ++r) { acc[r].x = 0.f; acc[r].y = 0.f; acc[r].z = 0.f; acc[r].w = 0.f; }
  const float4* sa4 = (const float4*)s_a;
  #pragma unroll 2
  for (int k4 = kq * 8; k4 < kq * 8 + 8; ++k4) {
    const float4 w0 = W4[(k4 * 4 + 0) * 128];
    const float4 w1 = W4[(k4 * 4 + 1) * 128];
    const float4 w2 = W4[(k4 * 4 + 2) * 128];
    const float4 w3 = W4[(k4 * 4 + 3) * 128];
    #pragma unroll
    for (int r = 0; r < 6; ++r) {
      const float4 a4 = sa4[r * 128 + k4];
      F4FMA(acc[r], a4.x, w0); F4FMA(acc[r], a4.y, w1);
      F4FMA(acc[r], a4.z, w2); F4FMA(acc[r], a4.w, w3);
    }
  }
  #pragma unroll
  for (int r = 0; r < 6; ++r) s_p[(kq * 6 + r) * 16 + cq] = acc[r];
  __syncthreads();
  if (tid < 96) {
    const int r = tid >> 4, c = tid & 15;
    float4 s = s_p[r * 16 + c];
    #pragma unroll
    for (int q = 1; q < 16; ++q) {
      const float4 p = s_p[(q * 6 + r) * 16 + c];
      s.x += p.x; s.y += p.y; s.z += p.z; s.w += p.w;
    }
    const float4 bv = ((const float4*)(bias + c0))[c];
    float4 o;
    o.x = fmaxf(s.x + bv.x, 0.f);
    o.y = fmaxf(s.y + bv.y, 0.f);
    o.z = fmaxf(s.z + bv.z, 0.f);
    o.w = fmaxf(s.w + bv.w, 0.f);
    ((float4*)(Out + (size_t)(r0 + r) * 512 + c0))[c] = o;
  }
}

// ---------------------------------------------------------------------------
// final: pool2 (per block) + ensemble + fc.  grid 8x256
// ---------------------------------------------------------------------------
__global__ __launch_bounds__(256) void k_final(
    const float* __restrict__ seq, const float* __restrict__ mask,
    const float* __restrict__ ws, const float* __restrict__ fcW,
    const float* __restrict__ fcb, float* __restrict__ out)
{
  __shared__ float s_ens[512];
  __shared__ float s_red[256];
  const int b = blockIdx.x, tid = threadIdx.x;
  const float* ensw = ws + ENSW_OFF;
  const float* rcnt = ws + CNT_OFF;
  const float* p0 = ws + POOL_OFF + b * 512;
  const float* p1 = ws + POOL_OFF + 4096 + b * 512;
  float2 acc; acc.x = 0.f; acc.y = 0.f;
  const float2* seqb2 = (const float2*)(seq + (size_t)b * 96 * 512);
  #pragma unroll 4
  for (int i = 0; i < 96; ++i) {
    const float m = mask[b * 96 + i];
    const float2 x = seqb2[i * 256 + tid];
    acc.x = fmaf(m, x.x, acc.x);
    acc.y = fmaf(m, x.y, acc.y);
  }
  const float rc = rcnt[b];
  const float w0 = ensw[0], w1 = ensw[1], w2 = ensw[2];
  s_ens[tid * 2]     = w0 * p0[tid * 2]     + w1 * p1[tid * 2]     + w2 * acc.x * rc;
  s_ens[tid * 2 + 1] = w0 * p0[tid * 2 + 1] + w1 * p1[tid * 2 + 1] + w2 * acc.y * rc;
  __syncthreads();
  const int r = tid & 63, dq = tid >> 6;
  float a = 0.f;
  #pragma unroll 4
  for (int d = dq * 128; d < dq * 128 + 128; ++d)
    a = fmaf(s_ens[d], fcW[d * 64 + r], a);
  s_red[tid] = a;
  __syncthreads();
  if (tid < 64)
    out[b * 64 + tid] = fcb[tid] + s_red[tid] + s_red[64 + tid]
                      + s_red[128 + tid] + s_red[192 + tid];
}

extern "C" void kernel_launch(void* const* d_in, const int* in_sizes, int n_in,
                              void* d_out, int out_size, void* d_ws, size_t ws_size,
                              hipStream_t stream)
{
  const float* text  = (const float*)d_in[0];
  const float* mask  = (const float*)d_in[1];
  const float* adj   = (const float*)d_in[2];
  const float* E     = (const float*)d_in[3];
  const float* gamma = (const float*)d_in[4];
  const float* beta  = (const float*)d_in[5];
  const float* Wst   = (const float*)d_in[6];
  const float* bst   = (const float*)d_in[7];
  const float* ensl  = (const float*)d_in[8];
  const float* fcW   = (const float*)d_in[9];
  const float* fcb   = (const float*)d_in[10];
  const int*   dv    = (const int*)d_in[11];
  float* ws  = (float*)d_ws;
  float* out = (float*)d_out;

  float* seq = ws + SEQ_OFF;
  float* agg = ws + AGG_OFF;

  k_prep<<<dim3(512), dim3(256), 0, stream>>>(text, mask, E, gamma, beta, ensl, ws);
  for (int l = 0; l < 3; ++l) {
    k_attn<<<dim3(784), dim3(256), 0, stream>>>(
        seq, agg, adj, E, dv, ws, mask,
        ws + POOL_OFF + (l > 0 ? (l - 1) * 4096 : 0), l > 0 ? 1 : 0);
    k_gemm<<<dim3(1024), dim3(256), 0, stream>>>(
        agg, Wst + l * 262144, bst + l * 512, seq);
  }
  k_final<<<dim3(8), dim3(256), 0, stream>>>(seq, mask, ws, fcW, fcb, out);
}